// Round 1
// baseline (128.308 us; speedup 1.0000x reference)
//
#include <hip/hip_runtime.h>
#include <math.h>

#define N_WIRES 12
#define DIM 4096
#define N_LAYERS 3
#define NTHREADS 256

// GF(2)-linear LDS slot swizzle: keeps bits 5..11, bank bits (0..4) are
// {i0^i4^i8, i1^i5^i9, i2^i6(^i10), i3^i7(^i11), i4^i9}. Rank-5 over the
// varying lane bits of all three pass patterns -> 2 lanes/bank (free).
__device__ __forceinline__ int swz(int i) {
  int lo4 = (i ^ (i >> 4) ^ (i >> 8)) & 15;
  int b4  = ((i >> 4) ^ (i >> 9)) & 1;
  return (i & ~31) | (b4 << 4) | lo4;
}

// Apply SU(2) gate [[a,b],[-b*,a*]] on register-resident 16-element slice,
// pairing elements differing in bit MASK of j. All indices compile-time.
template<int MASK>
__device__ __forceinline__ void gate(const float* __restrict__ ga, int gi,
                                     float* __restrict__ re, float* __restrict__ im) {
  float ar = ga[4*gi+0], ai = ga[4*gi+1], br = ga[4*gi+2], bi = ga[4*gi+3];
  #pragma unroll
  for (int j = 0; j < 16; ++j) {
    if ((j & MASK) == 0) {
      const int k = j | MASK;
      float v0r = re[j], v0i = im[j], v1r = re[k], v1i = im[k];
      re[j] =  ar*v0r - ai*v0i + br*v1r - bi*v1i;
      im[j] =  ar*v0i + ai*v0r + br*v1i + bi*v1r;
      re[k] = -br*v0r - bi*v0i + ar*v1r + ai*v1i;
      im[k] = -br*v0i + bi*v0r + ar*v1i - ai*v1r;
    }
  }
}

__global__ __launch_bounds__(NTHREADS)
void qsim_kernel(const float* __restrict__ in, const float* __restrict__ params,
                 const float* __restrict__ hw, const float* __restrict__ hb,
                 float* __restrict__ out) {
  __shared__ float sre[DIM];
  __shared__ float sim[DIM];
  __shared__ float ga[36*4];   // fused RZ@RY@RX per gate: a.re, a.im, b.re, b.im
  __shared__ float clow[16];   // <Z> coefficient, low-4-bit part
  __shared__ float red[4];

  const int t = threadIdx.x;
  const int b = blockIdx.x;

  // Fused gate matrices: M = RZ@RY@RX = [[a,b],[-b*,a*]],
  // a = e*(cy*cx + i*sy*sx), b = -e*(sy*cx + i*cy*sx), e = cz - i*sz (half angles)
  if (t < 36) {
    const float* P = params + t*3;
    float hx = P[0]*0.5f, hy = P[1]*0.5f, hz = P[2]*0.5f;
    float cx = cosf(hx), sx = sinf(hx);
    float cy = cosf(hy), sy = sinf(hy);
    float cz = cosf(hz), sz = sinf(hz);
    float arr = cy*cx, aii = sy*sx;
    float brr = sy*cx, bii = cy*sx;
    ga[4*t+0] =  cz*arr + sz*aii;
    ga[4*t+1] =  cz*aii - sz*arr;
    ga[4*t+2] = -(cz*brr + sz*bii);
    ga[4*t+3] = -(cz*bii - sz*brr);
  }
  if (t >= 64 && t < 80) {     // different wave than gate-computers
    int j = t - 64;
    float v = 0.f;
    #pragma unroll
    for (int p = 0; p < 4; ++p) v += hw[11-p] * (1.0f - 2.0f*((j>>p)&1));
    clow[j] = v;
  }

  // ---- load (coalesced float4) + norm reduction ----
  float re[16], im[16];
  const float* inb = in + (size_t)b * DIM;
  float ss = 0.f;
  #pragma unroll
  for (int q = 0; q < 4; ++q) {
    float4 v = reinterpret_cast<const float4*>(inb)[t*4 + q];
    re[4*q+0]=v.x; re[4*q+1]=v.y; re[4*q+2]=v.z; re[4*q+3]=v.w;
    ss += v.x*v.x + v.y*v.y + v.z*v.z + v.w*v.w;
  }
  #pragma unroll
  for (int o = 1; o < 64; o <<= 1) ss += __shfl_xor(ss, o, 64);
  if ((t & 63) == 0) red[t >> 6] = ss;
  __syncthreads();             // also publishes ga / clow
  float inv = 1.0f / sqrtf(red[0]+red[1]+red[2]+red[3]);
  #pragma unroll
  for (int j = 0; j < 16; ++j) { re[j] *= inv; im[j] = 0.f; }

  // Per-pass swizzled base addresses (S is XOR-linear: S(x^y)=S(x)^S(y))
  const int base1 = swz(t << 4);                         // pass1: i = t*16 + j
  const int base2 = swz(((t >> 4) << 8) | (t & 15));     // pass2: i = hi*256 + j*16 + lo
  const int base3 = swz(t);                              // pass3: i = j*256 + t
  const int pbase = swz((t << 4) ^ (t << 3));            // CNOT-chain permuted read

  for (int layer = 0; layer < N_LAYERS; ++layer) {
    const int g0 = layer * 12;
    if (layer > 0) {
      // fused CNOT chain of previous layer: new[i] = old[i ^ (i>>1)]
      #pragma unroll
      for (int j = 0; j < 16; ++j) {
        int a = pbase ^ (j ^ (j >> 1));
        re[j] = sre[a]; im[j] = sim[a];
      }
    }
    // ---- pass 1: wires 8..11 (i bits 3..0 = j bits 3..0) ----
    gate<8>(ga, g0+8,  re, im);
    gate<4>(ga, g0+9,  re, im);
    gate<2>(ga, g0+10, re, im);
    gate<1>(ga, g0+11, re, im);
    if (layer > 0) __syncthreads();  // permuted reads done before overwriting
    #pragma unroll
    for (int j = 0; j < 16; ++j) { int a = base1 ^ j; sre[a] = re[j]; sim[a] = im[j]; }
    __syncthreads();
    // ---- pass 2: wires 4..7 (i bits 7..4 = j bits 3..0) ----
    #pragma unroll
    for (int j = 0; j < 16; ++j) { int a = base2 ^ (17*j); re[j] = sre[a]; im[j] = sim[a]; }
    gate<8>(ga, g0+4, re, im);
    gate<4>(ga, g0+5, re, im);
    gate<2>(ga, g0+6, re, im);
    gate<1>(ga, g0+7, re, im);
    #pragma unroll
    for (int j = 0; j < 16; ++j) { int a = base2 ^ (17*j); sre[a] = re[j]; sim[a] = im[j]; }
    __syncthreads();
    // ---- pass 3: wires 0..3 (i bits 11..8 = j bits 3..0) ----
    #pragma unroll
    for (int j = 0; j < 16; ++j) { int a = base3 ^ ((j<<8)|((j&2)<<3)|j); re[j] = sre[a]; im[j] = sim[a]; }
    gate<8>(ga, g0+0, re, im);
    gate<4>(ga, g0+1, re, im);
    gate<2>(ga, g0+2, re, im);
    gate<1>(ga, g0+3, re, im);
    #pragma unroll
    for (int j = 0; j < 16; ++j) { int a = base3 ^ ((j<<8)|((j&2)<<3)|j); sre[a] = re[j]; sim[a] = im[j]; }
    __syncthreads();
  }

  // ---- readout: sum |amp|^2 * c(i), with last CNOT chain fused into read ----
  float ct = 0.f;
  #pragma unroll
  for (int p = 0; p < 8; ++p) ct += hw[7-p] * (1.0f - 2.0f*((t>>p)&1));
  float acc = 0.f;
  #pragma unroll
  for (int j = 0; j < 16; ++j) {
    int a = pbase ^ (j ^ (j >> 1));
    float rr = sre[a], ii = sim[a];
    acc += (rr*rr + ii*ii) * (ct + clow[j]);
  }
  #pragma unroll
  for (int o = 1; o < 64; o <<= 1) acc += __shfl_xor(acc, o, 64);
  if ((t & 63) == 0) red[t >> 6] = acc;
  __syncthreads();
  if (t == 0) out[b] = red[0]+red[1]+red[2]+red[3] + hb[0];
}

extern "C" void kernel_launch(void* const* d_in, const int* in_sizes, int n_in,
                              void* d_out, int out_size, void* d_ws, size_t ws_size,
                              hipStream_t stream) {
  const float* st     = (const float*)d_in[0];
  const float* params = (const float*)d_in[1];
  const float* hw     = (const float*)d_in[2];
  const float* hb     = (const float*)d_in[3];
  float* out = (float*)d_out;
  int batch = in_sizes[0] / DIM;
  qsim_kernel<<<batch, NTHREADS, 0, stream>>>(st, params, hw, hb, out);
}